// Round 13
// baseline (521.367 us; speedup 1.0000x reference)
//
#include <hip/hip_runtime.h>

typedef __bf16 bf16;
typedef __bf16 bf16x8 __attribute__((ext_vector_type(8)));
typedef float floatx4 __attribute__((ext_vector_type(4)));
typedef float floatx16 __attribute__((ext_vector_type(16)));
typedef unsigned int uint;

#define MFMA16(a, b, c) __builtin_amdgcn_mfma_f32_16x16x32_bf16((a), (b), (c), 0, 0, 0)
#define MFMA32(a, b, c) __builtin_amdgcn_mfma_f32_32x32x16_bf16((a), (b), (c), 0, 0, 0)

// async global->LDS, 16B per lane. LDS side is wave-uniform base (lane0) + lane*16.
__device__ __forceinline__ void gl2lds16(const bf16* g, bf16* l) {
  __builtin_amdgcn_global_load_lds(
      (const __attribute__((address_space(1))) void*)g,
      (__attribute__((address_space(3))) void*)l, 16, 0, 0);
}
// s_waitcnt with vmcnt=N, lgkm=15, exp=7
__device__ __forceinline__ void wait_vm0() { __builtin_amdgcn_s_waitcnt(0x0f70); }

// split-KV partial slot -> pointer (slots 0..511 in d_out's `out` region,
// 512..1023 in the dead xb/wqb workspace region)
__device__ __forceinline__ float* slot_ptr(int s, float* o0, float* o1) {
  return s < 512 ? o0 + (size_t)s * 8192 : o1 + (size_t)(s - 512) * 8192;
}
__device__ __forceinline__ const float* slot_ptr_c(int s, const float* o0,
                                                   const float* o1) {
  return s < 512 ? o0 + (size_t)s * 8192 : o1 + (size_t)(s - 512) * 8192;
}

// ---------------------------------------------------------------------------
// fp32 -> bf16 ingest: x | wq | wk | wv. Also zeroes the 384 split-KV fixup
// counters (block 0) -- convert runs two launches before flash, so the
// counters are guaranteed zero when flash starts.
// ---------------------------------------------------------------------------
__device__ __forceinline__ void cvt8(const float* __restrict__ s,
                                     bf16* __restrict__ d, int i8) {
  const float4 a = ((const float4*)s)[i8 * 2];
  const float4 b = ((const float4*)s)[i8 * 2 + 1];
  bf16x8 o;
  o[0] = (bf16)a.x; o[1] = (bf16)a.y; o[2] = (bf16)a.z; o[3] = (bf16)a.w;
  o[4] = (bf16)b.x; o[5] = (bf16)b.y; o[6] = (bf16)b.z; o[7] = (bf16)b.w;
  *(bf16x8*)(d + i8 * 8) = o;
}

__global__ __launch_bounds__(256) void convert_kernel(
    const float* __restrict__ x, const float* __restrict__ wq,
    const float* __restrict__ wk, const float* __restrict__ wv,
    bf16* __restrict__ xb, bf16* __restrict__ wqb, bf16* __restrict__ wkb,
    bf16* __restrict__ wvb, uint* __restrict__ cnt) {
  const int g = blockIdx.x * 256 + threadIdx.x;
  if (g < 524288) cvt8(x, xb, g);
  else if (g < 1048576) cvt8(wq, wqb, g - 524288);
  else if (g < 1179648) cvt8(wk, wkb, g - 1048576);
  else cvt8(wv, wvb, g - 1179648);
  if (blockIdx.x == 0) {
    for (int i = threadIdx.x; i < 384; i += 256) cnt[i] = 0u;
  }
}

// ---------------------------------------------------------------------------
// 64x128xK GEMM tile body, BK=64 (round-4 structure) - used by gemm_o.
// ---------------------------------------------------------------------------
template <typename OutT>
__device__ __forceinline__ void gemm_tile_body64(
    const bf16* __restrict__ A, int lda,
    const bf16* __restrict__ B, int ldb,
    OutT* __restrict__ C, int ldc, int K,
    bf16* S) {  // 2 * 12288 bf16
  const int t = threadIdx.x;
  const int w = t >> 6, lane = t & 63;
  const int l15 = lane & 15, qd = lane >> 4;
  const int wr = w >> 1, wc = w & 1;

  floatx4 acc[2][4];
#pragma unroll
  for (int i = 0; i < 2; ++i)
#pragma unroll
    for (int j = 0; j < 4; ++j) acc[i][j] = (floatx4){0.f, 0.f, 0.f, 0.f};

  const bf16* gb[6];
  int lo[6];
#pragma unroll
  for (int i = 0; i < 6; ++i) {
    const int u = w + 4 * i;
    lo[i] = u * 512 + lane * 8;
    if (u < 8) {
      gb[i] = A + ((u >> 1) * 16 + l15) * lda + (u & 1) * 32 + qd * 8;
    } else {
      const int v = u - 8;
      gb[i] = B + ((v >> 1) * 16 + l15) * ldb + (v & 1) * 32 + qd * 8;
    }
  }

#define STG64(kt_, buf_)                                            \
  {                                                                 \
    bf16* d_ = S + (buf_) * 12288;                                  \
    _Pragma("unroll")                                               \
    for (int i_ = 0; i_ < 6; ++i_)                                  \
      gl2lds16(gb[i_] + (kt_) * 64, d_ + lo[i_]);                   \
  }

  const int NT = K >> 6;
  STG64(0, 0);
  wait_vm0();
  __syncthreads();
  int cur = 0;
  for (int kt = 0; kt < NT; ++kt) {
    if (kt + 1 < NT) STG64(kt + 1, cur ^ 1);  // issue next tile early
    const bf16* Ab = S + cur * 12288;
    const bf16* Bb = Ab + 4096;
    bf16x8 a[2][2], b[4][2];
#pragma unroll
    for (int i = 0; i < 2; ++i)
#pragma unroll
      for (int kk = 0; kk < 2; ++kk)
        a[i][kk] =
            *(const bf16x8*)(Ab + ((wr * 2 + i) * 2 + kk) * 512 + lane * 8);
#pragma unroll
    for (int j = 0; j < 4; ++j)
#pragma unroll
      for (int kk = 0; kk < 2; ++kk)
        b[j][kk] =
            *(const bf16x8*)(Bb + ((wc * 4 + j) * 2 + kk) * 512 + lane * 8);
#pragma unroll
    for (int kk = 0; kk < 2; ++kk)
#pragma unroll
      for (int i = 0; i < 2; ++i)
#pragma unroll
        for (int j = 0; j < 4; ++j)
          acc[i][j] = MFMA16(a[i][kk], b[j][kk], acc[i][j]);
    wait_vm0();
    __builtin_amdgcn_sched_barrier(0);
    __builtin_amdgcn_s_barrier();
    __builtin_amdgcn_sched_barrier(0);
    cur ^= 1;
  }
#undef STG64

#pragma unroll
  for (int i = 0; i < 2; ++i)
#pragma unroll
    for (int j = 0; j < 4; ++j) {
      const int row = wr * 32 + i * 16 + qd * 4;
      const int col = wc * 64 + j * 16 + l15;
#pragma unroll
      for (int r = 0; r < 4; ++r)
        C[(row + r) * ldc + col] = (OutT)acc[i][j][r];
    }
}

// ---------------------------------------------------------------------------
// Fused QKV projection + RoPE + V^T build. BK=64 main loop, LDS-staged
// vectorized epilogue (round-12 proven). T1 XCD-chunked swizzle kept.
// ---------------------------------------------------------------------------
__global__ __launch_bounds__(256) void gemm_qkv(
    const bf16* __restrict__ x, const bf16* __restrict__ wq,
    const bf16* __restrict__ wk, const bf16* __restrict__ wv,
    bf16* __restrict__ Qws, bf16* __restrict__ Kh, bf16* __restrict__ Vh,
    bf16* __restrict__ Vt) {
  __shared__ bf16 SM[17152];  // loop: As=SM[0..8191], Bs=SM[8192..16383];
                              // epilogue: 128 x 134-stride tile (34304 B)
  bf16* As = SM;
  bf16* Bs = SM + 8192;
  const int bid = blockIdx.y * 24 + blockIdx.x;
  const int swz = (bid & 7) * 48 + (bid >> 3);
  const int nb = swz % 24;
  const int m0 = (swz / 24) * 128;
  const bf16* B;
  if (nb < 16) B = wq + nb * 128 * 2048;
  else if (nb < 20) B = wk + (nb - 16) * 128 * 2048;
  else B = wv + (nb - 20) * 128 * 2048;

  const int t = threadIdx.x;
  const int w = t >> 6, lane = t & 63;
  const int l15 = lane & 15, qd = lane >> 4;
  const int wr = w >> 1, wc = w & 1;

  floatx4 acc[4][4];
#pragma unroll
  for (int i = 0; i < 4; ++i)
#pragma unroll
    for (int j = 0; j < 4; ++j) acc[i][j] = (floatx4){0.f, 0.f, 0.f, 0.f};

  const bf16* A = x + m0 * 2048;
  const int mt0 = w, mt1 = w + 4;
  const int kseg = qd * 8;
  const bf16* ga0 = A + (mt0 * 16 + l15) * 2048 + kseg;
  const bf16* ga1 = A + (mt1 * 16 + l15) * 2048 + kseg;
  const bf16* gb0 = B + (mt0 * 16 + l15) * 2048 + kseg;
  const bf16* gb1 = B + (mt1 * 16 + l15) * 2048 + kseg;
  bf16* lA00 = As + (mt0 * 2 + 0) * 512 + lane * 8;
  bf16* lA01 = As + (mt0 * 2 + 1) * 512 + lane * 8;
  bf16* lA10 = As + (mt1 * 2 + 0) * 512 + lane * 8;
  bf16* lA11 = As + (mt1 * 2 + 1) * 512 + lane * 8;
  bf16* lB00 = Bs + (mt0 * 2 + 0) * 512 + lane * 8;
  bf16* lB01 = Bs + (mt0 * 2 + 1) * 512 + lane * 8;
  bf16* lB10 = Bs + (mt1 * 2 + 0) * 512 + lane * 8;
  bf16* lB11 = Bs + (mt1 * 2 + 1) * 512 + lane * 8;

  for (int k0 = 0; k0 < 2048; k0 += 64) {
    gl2lds16(ga0 + k0, lA00);
    gl2lds16(ga0 + k0 + 32, lA01);
    gl2lds16(ga1 + k0, lA10);
    gl2lds16(ga1 + k0 + 32, lA11);
    gl2lds16(gb0 + k0, lB00);
    gl2lds16(gb0 + k0 + 32, lB01);
    gl2lds16(gb1 + k0, lB10);
    gl2lds16(gb1 + k0 + 32, lB11);
    wait_vm0();
    __syncthreads();

    bf16x8 a[4][2], b[4][2];
#pragma unroll
    for (int i = 0; i < 4; ++i)
#pragma unroll
      for (int kk = 0; kk < 2; ++kk)
        a[i][kk] =
            *(const bf16x8*)(As + ((wr * 4 + i) * 2 + kk) * 512 + lane * 8);
#pragma unroll
    for (int j = 0; j < 4; ++j)
#pragma unroll
      for (int kk = 0; kk < 2; ++kk)
        b[j][kk] =
            *(const bf16x8*)(Bs + ((wc * 4 + j) * 2 + kk) * 512 + lane * 8);
#pragma unroll
    for (int kk = 0; kk < 2; ++kk)
#pragma unroll
      for (int i = 0; i < 4; ++i)
#pragma unroll
        for (int j = 0; j < 4; ++j)
          acc[i][j] = MFMA16(a[i][kk], b[j][kk], acc[i][j]);
    __syncthreads();
  }

  // ---- epilogue pass 1: acc -> LDS tile (stride 134) ----
#pragma unroll
  for (int i = 0; i < 4; ++i)
#pragma unroll
    for (int j = 0; j < 4; ++j) {
      const int row = wr * 64 + i * 16 + qd * 4;
      const int col = wc * 64 + j * 16 + l15;
#pragma unroll
      for (int r = 0; r < 4; ++r)
        SM[(row + r) * 134 + col] = (bf16)acc[i][j][r];
    }
  __syncthreads();

  // ---- epilogue pass 2: vectorized roped stores ----
  const float NEG_LOG2_10000_D32 = -0.4152410118609203f;  // -log2(10000)/32
  if (nb < 16) {  // Q: rope -> Qws
#pragma unroll
    for (int k = 0; k < 8; ++k) {
      const int u = t + (k << 8);
      const int row = u >> 4, c8 = (u & 15) << 3;
      const bf16x8 v = *(const bf16x8*)&SM[row * 134 + c8];
      const float base = (float)(m0 + row + 1);
      bf16x8 ov;
#pragma unroll
      for (int p = 0; p < 4; ++p) {
        const int a = ((c8 & 63) >> 1) + p;
        float s, c;
        __sincosf(base * exp2f(NEG_LOG2_10000_D32 * (float)a), &s, &c);
        const float x0 = (float)v[2 * p], x1 = (float)v[2 * p + 1];
        ov[2 * p] = (bf16)(c * x0 - s * x1);
        ov[2 * p + 1] = (bf16)(s * x0 + c * x1);
      }
      *(bf16x8*)&Qws[(m0 + row) * 2048 + nb * 128 + c8] = ov;
    }
  } else if (nb < 20) {  // K: rope -> Kh
#pragma unroll
    for (int k = 0; k < 8; ++k) {
      const int u = t + (k << 8);
      const int row = u >> 4, c8 = (u & 15) << 3;
      const bf16x8 v = *(const bf16x8*)&SM[row * 134 + c8];
      const float base = (float)(m0 + row + 1);
      bf16x8 ov;
#pragma unroll
      for (int p = 0; p < 4; ++p) {
        const int a = ((c8 & 63) >> 1) + p;
        float s, c;
        __sincosf(base * exp2f(NEG_LOG2_10000_D32 * (float)a), &s, &c);
        const float x0 = (float)v[2 * p], x1 = (float)v[2 * p + 1];
        ov[2 * p] = (bf16)(c * x0 - s * x1);
        ov[2 * p + 1] = (bf16)(s * x0 + c * x1);
      }
      const int g512 = (nb - 16) * 128 + c8;
      const int kvh = g512 >> 6, d8 = g512 & 63;
      *(bf16x8*)&Kh[(kvh * 2048 + m0 + row) * 64 + d8] = ov;
    }
  } else {  // V: row-major Vh + transposed Vt
#pragma unroll
    for (int k = 0; k < 8; ++k) {
      const int u = t + (k << 8);
      const int row = u >> 4, c8 = (u & 15) << 3;
      const bf16x8 v = *(const bf16x8*)&SM[row * 134 + c8];
      const int g512 = (nb - 20) * 128 + c8;
      const int kvh = g512 >> 6, d8 = g512 & 63;
      *(bf16x8*)&Vh[(kvh * 2048 + m0 + row) * 64 + d8] = v;
    }
#pragma unroll
    for (int k = 0; k < 8; ++k) {
      const int u = t + (k << 8);
      const int col = u >> 4, r8 = (u & 15) << 3;
      bf16x8 v;
#pragma unroll
      for (int jj = 0; jj < 8; ++jj) v[jj] = SM[(r8 + jj) * 134 + col];
      const int g512 = (nb - 20) * 128 + col;
      const int kvh = g512 >> 6, d = g512 & 63;
      *(bf16x8*)&Vt[kvh * 131072 + d * 2048 + m0 + r8] = v;
    }
  }
}

// ---------------------------------------------------------------------------
// Output projection: O(2048x2048) @ Wo^T -> d_out[0:4194304] (fp32), plus the
// GQA x4 kout/vout expansion appended AFTER the K-loop. T1 swizzle kept.
// ---------------------------------------------------------------------------
__global__ __launch_bounds__(256) void gemm_o(
    const bf16* __restrict__ Ows, const bf16* __restrict__ wo,
    float* __restrict__ out, const bf16* __restrict__ Kh,
    const bf16* __restrict__ Vh, float* __restrict__ kout,
    float* __restrict__ vout) {
  __shared__ bf16 S[24576];
  const int bid = blockIdx.y * 16 + blockIdx.x;
  const int swz = (bid & 7) * 64 + (bid >> 3);
  const int n0 = (swz & 15) * 128;
  const int m0 = (swz >> 4) * 64;
  gemm_tile_body64<float>(Ows + m0 * 2048, 2048, wo + n0 * 2048, 2048,
                          out + m0 * 2048 + n0, 2048, 2048, S);

  // GQA x4 repeat expansion (fire-and-forget stores; 2 units/thread)
  const int g = bid * 256 + (int)threadIdx.x;  // 0..131071
  for (uint u = (uint)g; u < 262144u; u += 131072u) {
    const uint u2 = u & 131071u;
    const bf16* src = (u < 131072u) ? Kh : Vh;
    float* dst = (u < 131072u) ? kout : vout;
    const int kvh2 = u2 >> 14;
    const int rr = u2 & 16383;
    const int l = rr >> 3, d8 = (rr & 7) * 8;
    const bf16x8 v = *(const bf16x8*)(src + (kvh2 * 2048 + l) * 64 + d8);
    float4 f0, f1;
    f0.x = (float)v[0]; f0.y = (float)v[1]; f0.z = (float)v[2]; f0.w = (float)v[3];
    f1.x = (float)v[4]; f1.y = (float)v[5]; f1.z = (float)v[6]; f1.w = (float)v[7];
#pragma unroll
    for (int rep = 0; rep < 4; ++rep) {
      float* o2 = dst + (((kvh2 * 4 + rep) * 2048 + l) * 64 + d8);
      *(float4*)o2 = f0;
      *(float4*)(o2 + 4) = f1;
    }
  }
}

// ---------------------------------------------------------------------------
// Flash attention v8: round-12 structure + INLINE split-KV combine (split-K
// fixup): each (h,qt>=4) group has a device-scope counter; partial blocks
// store fp32 O^T + (m,l), release-fence, atomicAdd; the LAST segment block
// acquire-fences and performs the combine inline (SMEM reused as Osh).
// Removes the separate combine_kernel launch. wo conversion tail kept.
// ---------------------------------------------------------------------------
__global__ __launch_bounds__(256) void flash_kernel(
    const bf16* __restrict__ Qws, const bf16* __restrict__ Kh,
    const bf16* __restrict__ Vt, bf16* __restrict__ Ows,
    float* __restrict__ Op0, float* __restrict__ Op1, float* __restrict__ ML,
    uint* __restrict__ cnt, const float* __restrict__ wo,
    bf16* __restrict__ wob) {
  __shared__ bf16 SMEM[16384];  // loop: KVs[2][2][4096]; epilogue: Osh 128x66
  __shared__ int s_last;

  const int h = blockIdx.y;
  const int bx = 35 - (int)blockIdx.x;  // longest-first dispatch order
  int qt, seg, kts, kte, slot, nseg;
  if (bx < 4) {
    qt = bx; seg = -1; kts = 0; kte = 2 * qt + 2; slot = -1; nseg = 1;
  } else if (bx < 12) {
    const int j = bx - 4;
    qt = 4 + (j >> 1); seg = j & 1; nseg = 2;
    const int nkt = 2 * qt + 2;
    kts = seg * nkt / 2; kte = (seg + 1) * nkt / 2;
    slot = h * 32 + (bx - 4);
  } else {
    const int j = bx - 12;
    qt = 8 + j / 3; seg = j % 3; nseg = 3;
    const int nkt = 2 * qt + 2;
    kts = seg * nkt / 3; kte = (seg + 1) * nkt / 3;
    slot = h * 32 + (bx - 4);
  }
  const int kh = h >> 2;  // GQA interleaved repeat
  const int q0 = qt * 128;
  const int t = threadIdx.x, w = t >> 6, lane = t & 63;
  const int l31 = lane & 31, hf = lane >> 5;
  const int qw = q0 + w * 32;  // wave's q base; lane's q = qw + l31

  // staging: wave w stages K slots {w, w+4} and V slots {w, w+4}
  const int s0 = w, s1 = w + 4;
  const bf16* gK0 = Kh + kh * 131072 + ((s0 >> 2) * 32 + l31) * 64 + (s0 & 3) * 16 + hf * 8;
  const bf16* gK1 = Kh + kh * 131072 + ((s1 >> 2) * 32 + l31) * 64 + (s1 & 3) * 16 + hf * 8;
  const bf16* gV0 = Vt + kh * 131072 + ((s0 >> 2) * 32 + l31) * 2048 + (s0 & 3) * 16 + hf * 8;
  const bf16* gV1 = Vt + kh * 131072 + ((s1 >> 2) * 32 + l31) * 2048 + (s1 & 3) * 16 + hf * 8;

  // prologue: stage kt=kts into buf (kts&1)
  {
    const int nb = kts & 1;
    gl2lds16(gK0 + kts * 4096, &SMEM[nb * 8192 + s0 * 512 + lane * 8]);
    gl2lds16(gK1 + kts * 4096, &SMEM[nb * 8192 + s1 * 512 + lane * 8]);
    gl2lds16(gV0 + kts * 64, &SMEM[nb * 8192 + 4096 + s0 * 512 + lane * 8]);
    gl2lds16(gV1 + kts * 64, &SMEM[nb * 8192 + 4096 + s1 * 512 + lane * 8]);
  }

  // Q B-fragments: B[k=d][n=q], lane (l31,hf) holds Q[qw+l31][c*16+hf*8+j]
  bf16x8 qf[4];
  {
    const bf16* qrow = Qws + (qw + l31) * 2048 + h * 64 + hf * 8;
#pragma unroll
    for (int c = 0; c < 4; ++c) qf[c] = *(const bf16x8*)(qrow + c * 16);
  }

  floatx16 o[2] = {};  // O^T[m=d' tile n][n=q]: col = q = l31 (lane-owned)
  float mrun = -3e38f, lrun = 0.f;

  const float C = 0.1803368801f;  // 0.125 * log2(e)
  for (int kt = kts; kt < kte; ++kt) {
    wait_vm0();
    __syncthreads();
    if (kt + 1 < kte) {  // prefetch next tile into other buffer
      const int nb = (kt + 1) & 1;
      const int koff = (kt + 1) * 4096, voff = (kt + 1) * 64;
      gl2lds16(gK0 + koff, &SMEM[nb * 8192 + s0 * 512 + lane * 8]);
      gl2lds16(gK1 + koff, &SMEM[nb * 8192 + s1 * 512 + lane * 8]);
      gl2lds16(gV0 + voff, &SMEM[nb * 8192 + 4096 + s0 * 512 + lane * 8]);
      gl2lds16(gV1 + voff, &SMEM[nb * 8192 + 4096 + s1 * 512 + lane * 8]);
    }
    const int kt64 = kt * 64;
    if (kt64 > qw + 31) continue;  // fully masked for this wave
    const bf16* Kb = &SMEM[(kt & 1) * 8192];
    const bf16* Vb = Kb + 4096;

    // S^T = K . Q^T : two 32-key tiles; C/D col = q, row = key local
    floatx16 st[2];
    __builtin_amdgcn_s_setprio(1);
#pragma unroll
    for (int tt = 0; tt < 2; ++tt) {
      floatx16 z = {};
#pragma unroll
      for (int c = 0; c < 4; ++c) {
        const bf16x8 kf = *(const bf16x8*)(Kb + (tt * 4 + c) * 512 + lane * 8);
        z = MFMA32(kf, qf[c], z);
      }
      st[tt] = z;
    }
    __builtin_amdgcn_s_setprio(0);
    // causal mask (diagonal region only); key = kt64+tt*32+(r&3)+8*(r>>2)+4*hf
    if (kt64 + 64 > qw) {
      const int myq = qw + l31;
#pragma unroll
      for (int tt = 0; tt < 2; ++tt)
#pragma unroll
        for (int r = 0; r < 16; ++r) {
          const int key = kt64 + tt * 32 + (r & 3) + 8 * (r >> 2) + 4 * hf;
          if (key > myq) st[tt][r] = -1e30f;
        }
    }
    // online softmax: lane-scalar m/l; 4-way tree max then hf-pair reduce
    float ma = -3e38f, mb = -3e38f, mc = -3e38f, md = -3e38f;
#pragma unroll
    for (int tt = 0; tt < 2; ++tt)
#pragma unroll
      for (int r = 0; r < 16; r += 4) {
        ma = fmaxf(ma, st[tt][r + 0]);
        mb = fmaxf(mb, st[tt][r + 1]);
        mc = fmaxf(mc, st[tt][r + 2]);
        md = fmaxf(md, st[tt][r + 3]);
      }
    float mx = fmaxf(fmaxf(ma, mb), fmaxf(mc, md));
    mx = fmaxf(mx, __shfl_xor(mx, 32));
    // defer-max (T13): skip rescale while P stays bounded by 2^8
    const bool defer = __all((mx - mrun) * C <= 8.f);
    if (!defer) {
      const float mn = fmaxf(mrun, mx);
      const float al = __builtin_amdgcn_exp2f((mrun - mn) * C);
      lrun *= al;
#pragma unroll
      for (int n = 0; n < 2; ++n)
#pragma unroll
        for (int r = 0; r < 16; ++r) o[n][r] *= al;
      mrun = mn;
    }
    float ra = 0.f, rb = 0.f, rc = 0.f, rd = 0.f;
#pragma unroll
    for (int tt = 0; tt < 2; ++tt)
#pragma unroll
      for (int r = 0; r < 16; r += 4) {
        const float p0 = __builtin_amdgcn_exp2f((st[tt][r + 0] - mrun) * C);
        const float p1 = __builtin_amdgcn_exp2f((st[tt][r + 1] - mrun) * C);
        const float p2 = __builtin_amdgcn_exp2f((st[tt][r + 2] - mrun) * C);
        const float p3 = __builtin_amdgcn_exp2f((st[tt][r + 3] - mrun) * C);
        st[tt][r + 0] = p0; ra += p0;
        st[tt][r + 1] = p1; rb += p1;
        st[tt][r + 2] = p2; rc += p2;
        st[tt][r + 3] = p3; rd += p3;
      }
    float rs = (ra + rb) + (rc + rd);
    rs += __shfl_xor(rs, 32);
    lrun += rs;

    // P^T B-frags from S^T C/D via half-exchange (owner hf = j>>2):
    uint pk[2][4][2];
#pragma unroll
    for (int tt = 0; tt < 2; ++tt)
#pragma unroll
      for (int g = 0; g < 4; ++g)
#pragma unroll
        for (int p = 0; p < 2; ++p) {
          union { bf16 h2[2]; uint u; } cv;
          cv.h2[0] = (bf16)st[tt][4 * g + 2 * p];
          cv.h2[1] = (bf16)st[tt][4 * g + 2 * p + 1];
          pk[tt][g][p] = cv.u;
        }
    uint own_[2][2][2], rv[2][2][2];
#pragma unroll
    for (int tt = 0; tt < 2; ++tt)
#pragma unroll
      for (int gam = 0; gam < 2; ++gam)
#pragma unroll
        for (int p = 0; p < 2; ++p) {
          own_[tt][gam][p] = hf ? pk[tt][2 * gam + 1][p] : pk[tt][2 * gam][p];
          const uint snd = hf ? pk[tt][2 * gam][p] : pk[tt][2 * gam + 1][p];
          rv[tt][gam][p] = (uint)__shfl_xor((int)snd, 32);
        }
    __builtin_amdgcn_s_setprio(1);
#pragma unroll
    for (int c = 0; c < 4; ++c) {
      const int tt = c >> 1, gam = c & 1;
      union { uint u[4]; bf16x8 v; } pf;
      pf.u[0] = hf ? rv[tt][gam][0] : own_[tt][gam][0];
      pf.u[1] = hf ? rv[tt][gam][1] : own_[tt][gam][1];
      pf.u[2] = hf ? own_[tt][gam][0] : rv[tt][gam][0];
      pf.u[3] = hf ? own_[tt][gam][1] : rv[tt][gam][1];
#pragma unroll
      for (int n = 0; n < 2; ++n)
        o[n] = MFMA32(*(const bf16x8*)(Vb + (n * 4 + c) * 512 + lane * 8),
                      pf.v, o[n]);
    }
    __builtin_amdgcn_s_setprio(0);
  }

  if (seg < 0) {
    // full block: normalize, O^T C/D -> LDS transpose -> coalesced store.
    __syncthreads();  // all waves done reading KVs before Osh aliases SMEM
    bf16* Osh = SMEM;
    const float inv = 1.f / lrun;
#pragma unroll
    for (int n = 0; n < 2; ++n)
#pragma unroll
      for (int r = 0; r < 16; ++r) {
        const int dl = n * 32 + (r & 3) + 8 * (r >> 2) + 4 * hf;
        Osh[(w * 32 + l31) * 66 + dl] = (bf16)(o[n][r] * inv);
      }
    __syncthreads();
#pragma unroll
    for (int i = 0; i < 4; ++i) {
      const int row = (t >> 3) + i * 32;
      const int col = (t & 7) * 8;
      const bf16x8 vv = *(const bf16x8*)&Osh[row * 66 + col];
      *(bf16x8*)&Ows[(q0 + row) * 2048 + h * 64 + col] = vv;
    }
  } else {
    // partial block: unnormalized fp32 O^T [d'][row] + per-row (m, l)
    float* Op = slot_ptr(slot, Op0, Op1);
#pragma unroll
    for (int n = 0; n < 2; ++n)
#pragma unroll
      for (int r = 0; r < 16; ++r) {
        const int dl = n * 32 + (r & 3) + 8 * (r >> 2) + 4 * hf;
        Op[dl * 128 + w * 32 + l31] = o[n][r];
      }
    if (hf == 0) {
      ML[slot * 256 + w * 32 + l31] = mrun;
      ML[slot * 256 + 128 + w * 32 + l31] = lrun;
    }

    // ---- split-K fixup: last segment block combines inline ----
    const int qi = qt - 4;
    const int cidx = h * 12 + qi;
    __threadfence();  // release: partial stores visible at device scope
    __syncthreads();
    if (t == 0) {
      const uint old = atomicAdd(&cnt[cidx], 1u);
      s_last = (old == (uint)(nseg - 1)) ? 1 : 0;
    }
    __syncthreads();
    if (s_last) {
      __threadfence();  // acquire: see other segments' partials
      const bool three = (nseg == 3);
      const int slot0 = h * 32 + (three ? 8 + qi * 3 - 12 : qi * 2);
      const int row = t & 127, dh = t >> 7;
      const float m0_ = ML[(slot0 + 0) * 256 + row];
      const float l0_ = ML[(slot0 + 0) * 256 + 128 + row];
      const float m1_ = ML[(slot0 + 1) * 256 + row];
      const float l1_ = ML[(slot0 + 1) * 256 + 128 + row];
      const float m2_ = three ? ML[(slot0 + 2) * 256 + row] : -3e38f;
      const float l2_ = three ? ML[(slot0 + 2) * 256 + 128 + row] : 0.f;
      const float m = fmaxf(fmaxf(m0_, m1_), m2_);
      const float w0_ = __builtin_amdgcn_exp2f((m0_ - m) * C);
      const float w1_ = __builtin_amdgcn_exp2f((m1_ - m) * C);
      const float w2_ = three ? __builtin_amdgcn_exp2f((m2_ - m) * C) : 0.f;
      const float inv = 1.f / (l0_ * w0_ + l1_ * w1_ + l2_ * w2_);
      const float* P0 = slot_ptr_c(slot0 + 0, Op0, Op1);
      const float* P1 = slot_ptr_c(slot0 + 1, Op0, Op1);
      const float* P2 = three ? slot_ptr_c(slot0 + 2, Op0, Op1) : P0;
      bf16* Osh = SMEM;  // loop staging fully consumed; safe after syncthreads
#pragma unroll
      for (int j = 0; j < 32; ++j) {
        const int d = dh * 32 + j;
        const float v = (P0[d * 128 + row] * w0_ + P1[d * 128 + row] * w1_ +
                         P2[d * 128 + row] * w2_) *
                        inv;
        Osh[row * 66 + d] = (bf16)v;
      }
      __syncthreads();
#pragma unroll
      for (int i = 0; i < 4; ++i) {
        const int r2 = (t >> 3) + i * 32;
        const int col = (t & 7) * 8;
        const bf16x8 vv = *(const bf16x8*)&Osh[r2 * 66 + col];
        *(bf16x8*)&Ows[(q0 + r2) * 2048 + h * 64 + col] = vv;
      }
    }
  }

  // ---- tail: wo fp32 -> bf16 (fire-and-forget; needed only by gemm_o) ----
  {
    const int bidf = (int)blockIdx.y * 36 + (int)blockIdx.x;  // 0..1151
    for (uint u = (uint)(bidf * 256 + t); u < 524288u; u += 294912u)
      cvt8(wo, wob, (int)u);
  }
}

// ---------------------------------------------------------------------------
extern "C" void kernel_launch(void* const* d_in, const int* in_sizes, int n_in,
                              void* d_out, int out_size, void* d_ws,
                              size_t ws_size, hipStream_t stream) {
  const float* x = (const float*)d_in[0];
  // d_in[1] = mask: causality recomputed in-kernel, unused.
  const float* wq = (const float*)d_in[2];
  const float* wk = (const float*)d_in[3];
  const float* wv = (const float*)d_in[4];
  const float* wo = (const float*)d_in[5];

  float* out = (float*)d_out;            // (2048, 2048) fp32
  float* kout = out + 4194304;           // (32, 2048, 64) fp32
  float* vout = out + 8388608;           // (32, 2048, 64) fp32

  bf16* ws = (bf16*)d_ws;
  bf16* xb = ws;                         // 2048 x 2048
  bf16* wqb = xb + 4194304;              // 2048 x 2048
  bf16* wkb = wqb + 4194304;             // 512 x 2048
  bf16* wvb = wkb + 1048576;             // 512 x 2048
  bf16* wob = wvb + 1048576;             // 2048 x 2048
  bf16* Qws = wob + 4194304;             // 2048 x 2048 (roped Q)
  bf16* Kws = Qws + 4194304;             // 2048 x 512 (ML + counters scratch)
  bf16* Vh = Kws + 1048576;              // 2048 x 512 region: V per-head rows
  bf16* Vt = Vh + 1048576;               // 8 x 64 x 2048 (V^T per kv head)
  bf16* Ows = Vt + 1048576;              // 2048 x 2048 (attention out)
  bf16* Kh = Ows + 4194304;              // 8 x 2048 x 64 (roped K per kv head)
  // Partial-slot regions (no new workspace): slots 0..511 in `out` (rewritten
  // by gemm_o), slots 512..1023 in the dead xb/wqb region (dead after
  // gemm_qkv); ML + fixup counters in the dead Kws region (2 MB total:
  // ML = 1 MB, counters 1.5 KB).
  float* Op0 = out;
  float* Op1 = (float*)ws;               // 512 slots x 8192 fp32
  float* MLf = (float*)Kws;              // 1024 x 256 fp32 (m,l partials)
  uint* cnt = (uint*)(MLf + 262144);     // 384 fixup counters

  convert_kernel<<<dim3(5120), dim3(256), 0, stream>>>(x, wq, wk, wv, xb, wqb,
                                                       wkb, wvb, cnt);
  gemm_qkv<<<dim3(24, 16), dim3(256), 0, stream>>>(xb, wqb, wkb, wvb, Qws, Kh,
                                                   Vh, Vt);
  flash_kernel<<<dim3(36, 32), dim3(256), 0, stream>>>(Qws, Kh, Vt, Ows, Op0,
                                                       Op1, MLf, cnt, wo, wob);
  gemm_o<<<dim3(16, 32), dim3(256), 0, stream>>>(Ows, wob, out, Kh, Vh, kout,
                                                 vout);
}

// Round 14
// 277.454 us; speedup vs baseline: 1.8791x; 1.8791x over previous
//
#include <hip/hip_runtime.h>

typedef __bf16 bf16;
typedef __bf16 bf16x8 __attribute__((ext_vector_type(8)));
typedef float floatx4 __attribute__((ext_vector_type(4)));
typedef float floatx16 __attribute__((ext_vector_type(16)));
typedef unsigned int uint;

#define MFMA16(a, b, c) __builtin_amdgcn_mfma_f32_16x16x32_bf16((a), (b), (c), 0, 0, 0)
#define MFMA32(a, b, c) __builtin_amdgcn_mfma_f32_32x32x16_bf16((a), (b), (c), 0, 0, 0)

// async global->LDS, 16B per lane. LDS side is wave-uniform base (lane0) + lane*16.
__device__ __forceinline__ void gl2lds16(const bf16* g, bf16* l) {
  __builtin_amdgcn_global_load_lds(
      (const __attribute__((address_space(1))) void*)g,
      (__attribute__((address_space(3))) void*)l, 16, 0, 0);
}
// s_waitcnt with vmcnt=N, lgkm=15, exp=7
__device__ __forceinline__ void wait_vm0() { __builtin_amdgcn_s_waitcnt(0x0f70); }

// split-KV partial slot -> pointer (slots 0..511 in d_out's `out` region,
// 512..1023 in the dead xb/wqb workspace region)
__device__ __forceinline__ float* slot_ptr(int s, float* o0, float* o1) {
  return s < 512 ? o0 + (size_t)s * 8192 : o1 + (size_t)(s - 512) * 8192;
}
__device__ __forceinline__ const float* slot_ptr_c(int s, const float* o0,
                                                   const float* o1) {
  return s < 512 ? o0 + (size_t)s * 8192 : o1 + (size_t)(s - 512) * 8192;
}

// ---------------------------------------------------------------------------
// fp32 -> bf16 ingest: x | wq | wk | wv (wo conversion folded into flash's
// tail -- it is only needed by gemm_o). 8 elems/thread.
// ---------------------------------------------------------------------------
__device__ __forceinline__ void cvt8(const float* __restrict__ s,
                                     bf16* __restrict__ d, int i8) {
  const float4 a = ((const float4*)s)[i8 * 2];
  const float4 b = ((const float4*)s)[i8 * 2 + 1];
  bf16x8 o;
  o[0] = (bf16)a.x; o[1] = (bf16)a.y; o[2] = (bf16)a.z; o[3] = (bf16)a.w;
  o[4] = (bf16)b.x; o[5] = (bf16)b.y; o[6] = (bf16)b.z; o[7] = (bf16)b.w;
  *(bf16x8*)(d + i8 * 8) = o;
}

__global__ __launch_bounds__(256) void convert_kernel(
    const float* __restrict__ x, const float* __restrict__ wq,
    const float* __restrict__ wk, const float* __restrict__ wv,
    bf16* __restrict__ xb, bf16* __restrict__ wqb, bf16* __restrict__ wkb,
    bf16* __restrict__ wvb) {
  const int g = blockIdx.x * 256 + threadIdx.x;
  if (g < 524288) cvt8(x, xb, g);
  else if (g < 1048576) cvt8(wq, wqb, g - 524288);
  else if (g < 1179648) cvt8(wk, wkb, g - 1048576);
  else cvt8(wv, wvb, g - 1179648);
}

// ---------------------------------------------------------------------------
// 64x128xK GEMM tile body, BK=64 (round-4 structure) - used by gemm_o.
// ---------------------------------------------------------------------------
template <typename OutT>
__device__ __forceinline__ void gemm_tile_body64(
    const bf16* __restrict__ A, int lda,
    const bf16* __restrict__ B, int ldb,
    OutT* __restrict__ C, int ldc, int K,
    bf16* S) {  // 2 * 12288 bf16
  const int t = threadIdx.x;
  const int w = t >> 6, lane = t & 63;
  const int l15 = lane & 15, qd = lane >> 4;
  const int wr = w >> 1, wc = w & 1;

  floatx4 acc[2][4];
#pragma unroll
  for (int i = 0; i < 2; ++i)
#pragma unroll
    for (int j = 0; j < 4; ++j) acc[i][j] = (floatx4){0.f, 0.f, 0.f, 0.f};

  const bf16* gb[6];
  int lo[6];
#pragma unroll
  for (int i = 0; i < 6; ++i) {
    const int u = w + 4 * i;
    lo[i] = u * 512 + lane * 8;
    if (u < 8) {
      gb[i] = A + ((u >> 1) * 16 + l15) * lda + (u & 1) * 32 + qd * 8;
    } else {
      const int v = u - 8;
      gb[i] = B + ((v >> 1) * 16 + l15) * ldb + (v & 1) * 32 + qd * 8;
    }
  }

#define STG64(kt_, buf_)                                            \
  {                                                                 \
    bf16* d_ = S + (buf_) * 12288;                                  \
    _Pragma("unroll")                                               \
    for (int i_ = 0; i_ < 6; ++i_)                                  \
      gl2lds16(gb[i_] + (kt_) * 64, d_ + lo[i_]);                   \
  }

  const int NT = K >> 6;
  STG64(0, 0);
  wait_vm0();
  __syncthreads();
  int cur = 0;
  for (int kt = 0; kt < NT; ++kt) {
    if (kt + 1 < NT) STG64(kt + 1, cur ^ 1);  // issue next tile early
    const bf16* Ab = S + cur * 12288;
    const bf16* Bb = Ab + 4096;
    bf16x8 a[2][2], b[4][2];
#pragma unroll
    for (int i = 0; i < 2; ++i)
#pragma unroll
      for (int kk = 0; kk < 2; ++kk)
        a[i][kk] =
            *(const bf16x8*)(Ab + ((wr * 2 + i) * 2 + kk) * 512 + lane * 8);
#pragma unroll
    for (int j = 0; j < 4; ++j)
#pragma unroll
      for (int kk = 0; kk < 2; ++kk)
        b[j][kk] =
            *(const bf16x8*)(Bb + ((wc * 4 + j) * 2 + kk) * 512 + lane * 8);
#pragma unroll
    for (int kk = 0; kk < 2; ++kk)
#pragma unroll
      for (int i = 0; i < 2; ++i)
#pragma unroll
        for (int j = 0; j < 4; ++j)
          acc[i][j] = MFMA16(a[i][kk], b[j][kk], acc[i][j]);
    wait_vm0();
    __builtin_amdgcn_sched_barrier(0);
    __builtin_amdgcn_s_barrier();
    __builtin_amdgcn_sched_barrier(0);
    cur ^= 1;
  }
#undef STG64

#pragma unroll
  for (int i = 0; i < 2; ++i)
#pragma unroll
    for (int j = 0; j < 4; ++j) {
      const int row = wr * 32 + i * 16 + qd * 4;
      const int col = wc * 64 + j * 16 + l15;
#pragma unroll
      for (int r = 0; r < 4; ++r)
        C[(row + r) * ldc + col] = (OutT)acc[i][j][r];
    }
}

// ---------------------------------------------------------------------------
// Fused QKV projection + RoPE + V^T build. BK=64 main loop (32 iterations:
// half the vmcnt(0)-drain + barrier events of BK=32; loop LDS 32 KB fits in
// the 34.3 KB epilogue region, so occupancy unchanged). LDS-staged
// vectorized epilogue (round-9/10 proven). T1 XCD-chunked swizzle kept.
// ---------------------------------------------------------------------------
__global__ __launch_bounds__(256) void gemm_qkv(
    const bf16* __restrict__ x, const bf16* __restrict__ wq,
    const bf16* __restrict__ wk, const bf16* __restrict__ wv,
    bf16* __restrict__ Qws, bf16* __restrict__ Kh, bf16* __restrict__ Vh,
    bf16* __restrict__ Vt) {
  __shared__ bf16 SM[17152];  // loop: As=SM[0..8191], Bs=SM[8192..16383];
                              // epilogue: 128 x 134-stride tile (34304 B)
  bf16* As = SM;
  bf16* Bs = SM + 8192;
  const int bid = blockIdx.y * 24 + blockIdx.x;
  const int swz = (bid & 7) * 48 + (bid >> 3);
  const int nb = swz % 24;
  const int m0 = (swz / 24) * 128;
  const bf16* B;
  if (nb < 16) B = wq + nb * 128 * 2048;
  else if (nb < 20) B = wk + (nb - 16) * 128 * 2048;
  else B = wv + (nb - 20) * 128 * 2048;

  const int t = threadIdx.x;
  const int w = t >> 6, lane = t & 63;
  const int l15 = lane & 15, qd = lane >> 4;
  const int wr = w >> 1, wc = w & 1;

  floatx4 acc[4][4];
#pragma unroll
  for (int i = 0; i < 4; ++i)
#pragma unroll
    for (int j = 0; j < 4; ++j) acc[i][j] = (floatx4){0.f, 0.f, 0.f, 0.f};

  const bf16* A = x + m0 * 2048;
  const int mt0 = w, mt1 = w + 4;
  const int kseg = qd * 8;
  // global row bases for the two m-tiles this wave stages (A and B)
  const bf16* ga0 = A + (mt0 * 16 + l15) * 2048 + kseg;
  const bf16* ga1 = A + (mt1 * 16 + l15) * 2048 + kseg;
  const bf16* gb0 = B + (mt0 * 16 + l15) * 2048 + kseg;
  const bf16* gb1 = B + (mt1 * 16 + l15) * 2048 + kseg;
  // LDS dests: fragment-ordered [mt][kk] blocks of 512 bf16
  bf16* lA00 = As + (mt0 * 2 + 0) * 512 + lane * 8;
  bf16* lA01 = As + (mt0 * 2 + 1) * 512 + lane * 8;
  bf16* lA10 = As + (mt1 * 2 + 0) * 512 + lane * 8;
  bf16* lA11 = As + (mt1 * 2 + 1) * 512 + lane * 8;
  bf16* lB00 = Bs + (mt0 * 2 + 0) * 512 + lane * 8;
  bf16* lB01 = Bs + (mt0 * 2 + 1) * 512 + lane * 8;
  bf16* lB10 = Bs + (mt1 * 2 + 0) * 512 + lane * 8;
  bf16* lB11 = Bs + (mt1 * 2 + 1) * 512 + lane * 8;

  for (int k0 = 0; k0 < 2048; k0 += 64) {
    gl2lds16(ga0 + k0, lA00);
    gl2lds16(ga0 + k0 + 32, lA01);
    gl2lds16(ga1 + k0, lA10);
    gl2lds16(ga1 + k0 + 32, lA11);
    gl2lds16(gb0 + k0, lB00);
    gl2lds16(gb0 + k0 + 32, lB01);
    gl2lds16(gb1 + k0, lB10);
    gl2lds16(gb1 + k0 + 32, lB11);
    wait_vm0();
    __syncthreads();

    bf16x8 a[4][2], b[4][2];
#pragma unroll
    for (int i = 0; i < 4; ++i)
#pragma unroll
      for (int kk = 0; kk < 2; ++kk)
        a[i][kk] =
            *(const bf16x8*)(As + ((wr * 4 + i) * 2 + kk) * 512 + lane * 8);
#pragma unroll
    for (int j = 0; j < 4; ++j)
#pragma unroll
      for (int kk = 0; kk < 2; ++kk)
        b[j][kk] =
            *(const bf16x8*)(Bs + ((wc * 4 + j) * 2 + kk) * 512 + lane * 8);
#pragma unroll
    for (int kk = 0; kk < 2; ++kk)
#pragma unroll
      for (int i = 0; i < 4; ++i)
#pragma unroll
        for (int j = 0; j < 4; ++j)
          acc[i][j] = MFMA16(a[i][kk], b[j][kk], acc[i][j]);
    __syncthreads();
  }

  // ---- epilogue pass 1: acc -> LDS tile (stride 134) ----
#pragma unroll
  for (int i = 0; i < 4; ++i)
#pragma unroll
    for (int j = 0; j < 4; ++j) {
      const int row = wr * 64 + i * 16 + qd * 4;
      const int col = wc * 64 + j * 16 + l15;
#pragma unroll
      for (int r = 0; r < 4; ++r)
        SM[(row + r) * 134 + col] = (bf16)acc[i][j][r];
    }
  __syncthreads();

  // ---- epilogue pass 2: vectorized roped stores ----
  const float NEG_LOG2_10000_D32 = -0.4152410118609203f;  // -log2(10000)/32
  if (nb < 16) {  // Q: rope -> Qws
#pragma unroll
    for (int k = 0; k < 8; ++k) {
      const int u = t + (k << 8);
      const int row = u >> 4, c8 = (u & 15) << 3;
      const bf16x8 v = *(const bf16x8*)&SM[row * 134 + c8];
      const float base = (float)(m0 + row + 1);
      bf16x8 ov;
#pragma unroll
      for (int p = 0; p < 4; ++p) {
        const int a = ((c8 & 63) >> 1) + p;
        float s, c;
        __sincosf(base * exp2f(NEG_LOG2_10000_D32 * (float)a), &s, &c);
        const float x0 = (float)v[2 * p], x1 = (float)v[2 * p + 1];
        ov[2 * p] = (bf16)(c * x0 - s * x1);
        ov[2 * p + 1] = (bf16)(s * x0 + c * x1);
      }
      *(bf16x8*)&Qws[(m0 + row) * 2048 + nb * 128 + c8] = ov;
    }
  } else if (nb < 20) {  // K: rope -> Kh
#pragma unroll
    for (int k = 0; k < 8; ++k) {
      const int u = t + (k << 8);
      const int row = u >> 4, c8 = (u & 15) << 3;
      const bf16x8 v = *(const bf16x8*)&SM[row * 134 + c8];
      const float base = (float)(m0 + row + 1);
      bf16x8 ov;
#pragma unroll
      for (int p = 0; p < 4; ++p) {
        const int a = ((c8 & 63) >> 1) + p;
        float s, c;
        __sincosf(base * exp2f(NEG_LOG2_10000_D32 * (float)a), &s, &c);
        const float x0 = (float)v[2 * p], x1 = (float)v[2 * p + 1];
        ov[2 * p] = (bf16)(c * x0 - s * x1);
        ov[2 * p + 1] = (bf16)(s * x0 + c * x1);
      }
      const int g512 = (nb - 16) * 128 + c8;
      const int kvh = g512 >> 6, d8 = g512 & 63;
      *(bf16x8*)&Kh[(kvh * 2048 + m0 + row) * 64 + d8] = ov;
    }
  } else {  // V: row-major Vh + transposed Vt
#pragma unroll
    for (int k = 0; k < 8; ++k) {
      const int u = t + (k << 8);
      const int row = u >> 4, c8 = (u & 15) << 3;
      const bf16x8 v = *(const bf16x8*)&SM[row * 134 + c8];
      const int g512 = (nb - 20) * 128 + c8;
      const int kvh = g512 >> 6, d8 = g512 & 63;
      *(bf16x8*)&Vh[(kvh * 2048 + m0 + row) * 64 + d8] = v;
    }
#pragma unroll
    for (int k = 0; k < 8; ++k) {
      const int u = t + (k << 8);
      const int col = u >> 4, r8 = (u & 15) << 3;
      bf16x8 v;
#pragma unroll
      for (int jj = 0; jj < 8; ++jj) v[jj] = SM[(r8 + jj) * 134 + col];
      const int g512 = (nb - 20) * 128 + col;
      const int kvh = g512 >> 6, d = g512 & 63;
      *(bf16x8*)&Vt[kvh * 131072 + d * 2048 + m0 + r8] = v;
    }
  }
}

// ---------------------------------------------------------------------------
// Output projection: O(2048x2048) @ Wo^T -> d_out[0:4194304] (fp32), plus the
// GQA x4 kout/vout expansion appended AFTER the K-loop (past the last
// vmcnt(0), so the stores never serialize with compute). T1 swizzle kept.
// ---------------------------------------------------------------------------
__global__ __launch_bounds__(256) void gemm_o(
    const bf16* __restrict__ Ows, const bf16* __restrict__ wo,
    float* __restrict__ out, const bf16* __restrict__ Kh,
    const bf16* __restrict__ Vh, float* __restrict__ kout,
    float* __restrict__ vout) {
  __shared__ bf16 S[24576];
  const int bid = blockIdx.y * 16 + blockIdx.x;
  const int swz = (bid & 7) * 64 + (bid >> 3);
  const int n0 = (swz & 15) * 128;
  const int m0 = (swz >> 4) * 64;
  gemm_tile_body64<float>(Ows + m0 * 2048, 2048, wo + n0 * 2048, 2048,
                          out + m0 * 2048 + n0, 2048, 2048, S);

  // GQA x4 repeat expansion (fire-and-forget stores; 2 units/thread)
  const int g = bid * 256 + (int)threadIdx.x;  // 0..131071
  for (uint u = (uint)g; u < 262144u; u += 131072u) {
    const uint u2 = u & 131071u;
    const bf16* src = (u < 131072u) ? Kh : Vh;
    float* dst = (u < 131072u) ? kout : vout;
    const int kvh2 = u2 >> 14;
    const int rr = u2 & 16383;
    const int l = rr >> 3, d8 = (rr & 7) * 8;
    const bf16x8 v = *(const bf16x8*)(src + (kvh2 * 2048 + l) * 64 + d8);
    float4 f0, f1;
    f0.x = (float)v[0]; f0.y = (float)v[1]; f0.z = (float)v[2]; f0.w = (float)v[3];
    f1.x = (float)v[4]; f1.y = (float)v[5]; f1.z = (float)v[6]; f1.w = (float)v[7];
#pragma unroll
    for (int rep = 0; rep < 4; ++rep) {
      float* o2 = dst + (((kvh2 * 4 + rep) * 2048 + l) * 64 + d8);
      *(float4*)o2 = f0;
      *(float4*)(o2 + 4) = f1;
    }
  }
}

// ---------------------------------------------------------------------------
// Flash attention v7 (round-12 proven): finer split-KV with LONGEST-FIRST
// dispatch + wo fp32->bf16 conversion folded into the tail. NO device-scope
// fences: round-13 showed __threadfence() per partial block costs ~6x the
// launch it saves on non-coherent per-XCD L2s -- the separate combine
// launch IS the cheap synchronization.
// ---------------------------------------------------------------------------
__global__ __launch_bounds__(256) void flash_kernel(
    const bf16* __restrict__ Qws, const bf16* __restrict__ Kh,
    const bf16* __restrict__ Vt, bf16* __restrict__ Ows,
    float* __restrict__ Op0, float* __restrict__ Op1, float* __restrict__ ML,
    const float* __restrict__ wo, bf16* __restrict__ wob) {
  __shared__ bf16 SMEM[16384];  // loop: KVs[2][2][4096]; epilogue: Osh 128x66

  const int h = blockIdx.y;
  const int bx = 35 - (int)blockIdx.x;  // longest-first dispatch order
  int qt, seg, kts, kte, slot;
  if (bx < 4) {
    qt = bx; seg = -1; kts = 0; kte = 2 * qt + 2; slot = -1;
  } else if (bx < 12) {
    const int j = bx - 4;
    qt = 4 + (j >> 1); seg = j & 1;
    const int nkt = 2 * qt + 2;
    kts = seg * nkt / 2; kte = (seg + 1) * nkt / 2;
    slot = h * 32 + (bx - 4);
  } else {
    const int j = bx - 12;
    qt = 8 + j / 3; seg = j % 3;
    const int nkt = 2 * qt + 2;
    kts = seg * nkt / 3; kte = (seg + 1) * nkt / 3;
    slot = h * 32 + (bx - 4);
  }
  const int kh = h >> 2;  // GQA interleaved repeat
  const int q0 = qt * 128;
  const int t = threadIdx.x, w = t >> 6, lane = t & 63;
  const int l31 = lane & 31, hf = lane >> 5;
  const int qw = q0 + w * 32;  // wave's q base; lane's q = qw + l31

  // staging: wave w stages K slots {w, w+4} and V slots {w, w+4}
  const int s0 = w, s1 = w + 4;
  const bf16* gK0 = Kh + kh * 131072 + ((s0 >> 2) * 32 + l31) * 64 + (s0 & 3) * 16 + hf * 8;
  const bf16* gK1 = Kh + kh * 131072 + ((s1 >> 2) * 32 + l31) * 64 + (s1 & 3) * 16 + hf * 8;
  const bf16* gV0 = Vt + kh * 131072 + ((s0 >> 2) * 32 + l31) * 2048 + (s0 & 3) * 16 + hf * 8;
  const bf16* gV1 = Vt + kh * 131072 + ((s1 >> 2) * 32 + l31) * 2048 + (s1 & 3) * 16 + hf * 8;

  // prologue: stage kt=kts into buf (kts&1)
  {
    const int nb = kts & 1;
    gl2lds16(gK0 + kts * 4096, &SMEM[nb * 8192 + s0 * 512 + lane * 8]);
    gl2lds16(gK1 + kts * 4096, &SMEM[nb * 8192 + s1 * 512 + lane * 8]);
    gl2lds16(gV0 + kts * 64, &SMEM[nb * 8192 + 4096 + s0 * 512 + lane * 8]);
    gl2lds16(gV1 + kts * 64, &SMEM[nb * 8192 + 4096 + s1 * 512 + lane * 8]);
  }

  // Q B-fragments: B[k=d][n=q], lane (l31,hf) holds Q[qw+l31][c*16+hf*8+j]
  bf16x8 qf[4];
  {
    const bf16* qrow = Qws + (qw + l31) * 2048 + h * 64 + hf * 8;
#pragma unroll
    for (int c = 0; c < 4; ++c) qf[c] = *(const bf16x8*)(qrow + c * 16);
  }

  floatx16 o[2] = {};  // O^T[m=d' tile n][n=q]: col = q = l31 (lane-owned)
  float mrun = -3e38f, lrun = 0.f;

  const float C = 0.1803368801f;  // 0.125 * log2(e)
  for (int kt = kts; kt < kte; ++kt) {
    wait_vm0();
    __syncthreads();
    if (kt + 1 < kte) {  // prefetch next tile into other buffer
      const int nb = (kt + 1) & 1;
      const int koff = (kt + 1) * 4096, voff = (kt + 1) * 64;
      gl2lds16(gK0 + koff, &SMEM[nb * 8192 + s0 * 512 + lane * 8]);
      gl2lds16(gK1 + koff, &SMEM[nb * 8192 + s1 * 512 + lane * 8]);
      gl2lds16(gV0 + voff, &SMEM[nb * 8192 + 4096 + s0 * 512 + lane * 8]);
      gl2lds16(gV1 + voff, &SMEM[nb * 8192 + 4096 + s1 * 512 + lane * 8]);
    }
    const int kt64 = kt * 64;
    if (kt64 > qw + 31) continue;  // fully masked for this wave
    const bf16* Kb = &SMEM[(kt & 1) * 8192];
    const bf16* Vb = Kb + 4096;

    // S^T = K . Q^T : two 32-key tiles; C/D col = q, row = key local
    floatx16 st[2];
    __builtin_amdgcn_s_setprio(1);
#pragma unroll
    for (int tt = 0; tt < 2; ++tt) {
      floatx16 z = {};
#pragma unroll
      for (int c = 0; c < 4; ++c) {
        const bf16x8 kf = *(const bf16x8*)(Kb + (tt * 4 + c) * 512 + lane * 8);
        z = MFMA32(kf, qf[c], z);
      }
      st[tt] = z;
    }
    __builtin_amdgcn_s_setprio(0);
    // causal mask (diagonal region only); key = kt64+tt*32+(r&3)+8*(r>>2)+4*hf
    if (kt64 + 64 > qw) {
      const int myq = qw + l31;
#pragma unroll
      for (int tt = 0; tt < 2; ++tt)
#pragma unroll
        for (int r = 0; r < 16; ++r) {
          const int key = kt64 + tt * 32 + (r & 3) + 8 * (r >> 2) + 4 * hf;
          if (key > myq) st[tt][r] = -1e30f;
        }
    }
    // online softmax: lane-scalar m/l; 4-way tree max then hf-pair reduce
    float ma = -3e38f, mb = -3e38f, mc = -3e38f, md = -3e38f;
#pragma unroll
    for (int tt = 0; tt < 2; ++tt)
#pragma unroll
      for (int r = 0; r < 16; r += 4) {
        ma = fmaxf(ma, st[tt][r + 0]);
        mb = fmaxf(mb, st[tt][r + 1]);
        mc = fmaxf(mc, st[tt][r + 2]);
        md = fmaxf(md, st[tt][r + 3]);
      }
    float mx = fmaxf(fmaxf(ma, mb), fmaxf(mc, md));
    mx = fmaxf(mx, __shfl_xor(mx, 32));
    // defer-max (T13): skip rescale while P stays bounded by 2^8
    const bool defer = __all((mx - mrun) * C <= 8.f);
    if (!defer) {
      const float mn = fmaxf(mrun, mx);
      const float al = __builtin_amdgcn_exp2f((mrun - mn) * C);
      lrun *= al;
#pragma unroll
      for (int n = 0; n < 2; ++n)
#pragma unroll
        for (int r = 0; r < 16; ++r) o[n][r] *= al;
      mrun = mn;
    }
    float ra = 0.f, rb = 0.f, rc = 0.f, rd = 0.f;
#pragma unroll
    for (int tt = 0; tt < 2; ++tt)
#pragma unroll
      for (int r = 0; r < 16; r += 4) {
        const float p0 = __builtin_amdgcn_exp2f((st[tt][r + 0] - mrun) * C);
        const float p1 = __builtin_amdgcn_exp2f((st[tt][r + 1] - mrun) * C);
        const float p2 = __builtin_amdgcn_exp2f((st[tt][r + 2] - mrun) * C);
        const float p3 = __builtin_amdgcn_exp2f((st[tt][r + 3] - mrun) * C);
        st[tt][r + 0] = p0; ra += p0;
        st[tt][r + 1] = p1; rb += p1;
        st[tt][r + 2] = p2; rc += p2;
        st[tt][r + 3] = p3; rd += p3;
      }
    float rs = (ra + rb) + (rc + rd);
    rs += __shfl_xor(rs, 32);
    lrun += rs;

    // P^T B-frags from S^T C/D via half-exchange (owner hf = j>>2):
    uint pk[2][4][2];
#pragma unroll
    for (int tt = 0; tt < 2; ++tt)
#pragma unroll
      for (int g = 0; g < 4; ++g)
#pragma unroll
        for (int p = 0; p < 2; ++p) {
          union { bf16 h2[2]; uint u; } cv;
          cv.h2[0] = (bf16)st[tt][4 * g + 2 * p];
          cv.h2[1] = (bf16)st[tt][4 * g + 2 * p + 1];
          pk[tt][g][p] = cv.u;
        }
    uint own_[2][2][2], rv[2][2][2];
#pragma unroll
    for (int tt = 0; tt < 2; ++tt)
#pragma unroll
      for (int gam = 0; gam < 2; ++gam)
#pragma unroll
        for (int p = 0; p < 2; ++p) {
          own_[tt][gam][p] = hf ? pk[tt][2 * gam + 1][p] : pk[tt][2 * gam][p];
          const uint snd = hf ? pk[tt][2 * gam][p] : pk[tt][2 * gam + 1][p];
          rv[tt][gam][p] = (uint)__shfl_xor((int)snd, 32);
        }
    __builtin_amdgcn_s_setprio(1);
#pragma unroll
    for (int c = 0; c < 4; ++c) {
      const int tt = c >> 1, gam = c & 1;
      union { uint u[4]; bf16x8 v; } pf;
      pf.u[0] = hf ? rv[tt][gam][0] : own_[tt][gam][0];
      pf.u[1] = hf ? rv[tt][gam][1] : own_[tt][gam][1];
      pf.u[2] = hf ? own_[tt][gam][0] : rv[tt][gam][0];
      pf.u[3] = hf ? own_[tt][gam][1] : rv[tt][gam][1];
#pragma unroll
      for (int n = 0; n < 2; ++n)
        o[n] = MFMA32(*(const bf16x8*)(Vb + (n * 4 + c) * 512 + lane * 8),
                      pf.v, o[n]);
    }
    __builtin_amdgcn_s_setprio(0);
  }

  if (seg < 0) {
    // full block: normalize, O^T C/D -> LDS transpose -> coalesced store.
    __syncthreads();  // all waves done reading KVs before Osh aliases SMEM
    bf16* Osh = SMEM;
    const float inv = 1.f / lrun;
#pragma unroll
    for (int n = 0; n < 2; ++n)
#pragma unroll
      for (int r = 0; r < 16; ++r) {
        const int dl = n * 32 + (r & 3) + 8 * (r >> 2) + 4 * hf;
        Osh[(w * 32 + l31) * 66 + dl] = (bf16)(o[n][r] * inv);
      }
    __syncthreads();
#pragma unroll
    for (int i = 0; i < 4; ++i) {
      const int row = (t >> 3) + i * 32;
      const int col = (t & 7) * 8;
      const bf16x8 vv = *(const bf16x8*)&Osh[row * 66 + col];
      *(bf16x8*)&Ows[(q0 + row) * 2048 + h * 64 + col] = vv;
    }
  } else {
    // partial block: unnormalized fp32 O^T [d'][row] + per-row (m, l)
    float* Op = slot_ptr(slot, Op0, Op1);
#pragma unroll
    for (int n = 0; n < 2; ++n)
#pragma unroll
      for (int r = 0; r < 16; ++r) {
        const int dl = n * 32 + (r & 3) + 8 * (r >> 2) + 4 * hf;
        Op[dl * 128 + w * 32 + l31] = o[n][r];
      }
    if (hf == 0) {
      ML[slot * 256 + w * 32 + l31] = mrun;
      ML[slot * 256 + 128 + w * 32 + l31] = lrun;
    }
  }

  // ---- tail: wo fp32 -> bf16 (fire-and-forget; needed only by gemm_o) ----
  {
    const int bidf = (int)blockIdx.y * 36 + (int)blockIdx.x;  // 0..1151
    for (uint u = (uint)(bidf * 256 + t); u < 524288u; u += 294912u)
      cvt8(wo, wob, (int)u);
  }
}

// ---------------------------------------------------------------------------
// Combine 2 or 3 KV-segment partials per (h, qt>=4). grid 384 = 32h x 12qt.
// ---------------------------------------------------------------------------
__global__ __launch_bounds__(256) void combine_kernel(
    const float* __restrict__ Op0, const float* __restrict__ Op1,
    const float* __restrict__ ML, bf16* __restrict__ Ows) {
  __shared__ bf16 Osh[128 * 66];
  const int b = blockIdx.x;
  const int h = b / 12, qi = b % 12;
  const int qt = 4 + qi;
  const int q0 = qt * 128;
  const bool three = (qi >= 4);
  const int slot0 = h * 32 + (three ? 8 + (qi - 4) * 3 : qi * 2);
  const int t = threadIdx.x;
  const int row = t & 127, dh = t >> 7;
  const float C = 0.1803368801f;  // 0.125 * log2(e)
  const float m0 = ML[(slot0 + 0) * 256 + row], l0 = ML[(slot0 + 0) * 256 + 128 + row];
  const float m1 = ML[(slot0 + 1) * 256 + row], l1 = ML[(slot0 + 1) * 256 + 128 + row];
  const float m2 = three ? ML[(slot0 + 2) * 256 + row] : -3e38f;
  const float l2 = three ? ML[(slot0 + 2) * 256 + 128 + row] : 0.f;
  const float m = fmaxf(fmaxf(m0, m1), m2);
  const float w0 = __builtin_amdgcn_exp2f((m0 - m) * C);
  const float w1 = __builtin_amdgcn_exp2f((m1 - m) * C);
  const float w2 = three ? __builtin_amdgcn_exp2f((m2 - m) * C) : 0.f;
  const float inv = 1.f / (l0 * w0 + l1 * w1 + l2 * w2);
  const float* P0 = slot_ptr_c(slot0 + 0, Op0, Op1);
  const float* P1 = slot_ptr_c(slot0 + 1, Op0, Op1);
  const float* P2 = three ? slot_ptr_c(slot0 + 2, Op0, Op1) : P0;
#pragma unroll
  for (int j = 0; j < 32; ++j) {
    const int d = dh * 32 + j;
    const float v = (P0[d * 128 + row] * w0 + P1[d * 128 + row] * w1 +
                     P2[d * 128 + row] * w2) *
                    inv;
    Osh[row * 66 + d] = (bf16)v;
  }
  __syncthreads();
#pragma unroll
  for (int i = 0; i < 4; ++i) {
    const int r2 = (t >> 3) + i * 32;
    const int col = (t & 7) * 8;
    const bf16x8 vv = *(const bf16x8*)&Osh[r2 * 66 + col];
    *(bf16x8*)&Ows[(q0 + r2) * 2048 + h * 64 + col] = vv;
  }
}

// ---------------------------------------------------------------------------
extern "C" void kernel_launch(void* const* d_in, const int* in_sizes, int n_in,
                              void* d_out, int out_size, void* d_ws,
                              size_t ws_size, hipStream_t stream) {
  const float* x = (const float*)d_in[0];
  // d_in[1] = mask: causality recomputed in-kernel, unused.
  const float* wq = (const float*)d_in[2];
  const float* wk = (const float*)d_in[3];
  const float* wv = (const float*)d_in[4];
  const float* wo = (const float*)d_in[5];

  float* out = (float*)d_out;            // (2048, 2048) fp32
  float* kout = out + 4194304;           // (32, 2048, 64) fp32
  float* vout = out + 8388608;           // (32, 2048, 64) fp32

  bf16* ws = (bf16*)d_ws;
  bf16* xb = ws;                         // 2048 x 2048
  bf16* wqb = xb + 4194304;              // 2048 x 2048
  bf16* wkb = wqb + 4194304;             // 512 x 2048
  bf16* wvb = wkb + 1048576;             // 512 x 2048
  bf16* wob = wvb + 1048576;             // 2048 x 2048
  bf16* Qws = wob + 4194304;             // 2048 x 2048 (roped Q)
  bf16* Kws = Qws + 4194304;             // 2048 x 512 (ML scratch)
  bf16* Vh = Kws + 1048576;              // 2048 x 512 region: V per-head rows
  bf16* Vt = Vh + 1048576;               // 8 x 64 x 2048 (V^T per kv head)
  bf16* Ows = Vt + 1048576;              // 2048 x 2048 (attention out)
  bf16* Kh = Ows + 4194304;              // 8 x 2048 x 64 (roped K per kv head)
  // Partial-slot regions (no new workspace): slots 0..511 in `out` (rewritten
  // by gemm_o), slots 512..1023 in the dead xb/wqb region (dead after
  // gemm_qkv); ML in the dead Kws region.
  float* Op0 = out;
  float* Op1 = (float*)ws;               // 512 slots x 8192 fp32 = xb + half wqb
  float* MLf = (float*)Kws;              // 1024 x 256 fp32 (m,l partials)

  convert_kernel<<<dim3(5120), dim3(256), 0, stream>>>(x, wq, wk, wv, xb, wqb,
                                                       wkb, wvb);
  gemm_qkv<<<dim3(24, 16), dim3(256), 0, stream>>>(xb, wqb, wkb, wvb, Qws, Kh,
                                                   Vh, Vt);
  flash_kernel<<<dim3(36, 32), dim3(256), 0, stream>>>(Qws, Kh, Vt, Ows, Op0,
                                                       Op1, MLf, wo, wob);
  combine_kernel<<<dim3(384), dim3(256), 0, stream>>>(Op0, Op1, MLf, Ows);
  gemm_o<<<dim3(16, 32), dim3(256), 0, stream>>>(Ows, wob, out, Kh, Vh, kout,
                                                 vout);
}